// Round 1
// baseline (62.202 us; speedup 1.0000x reference)
//
#include <hip/hip_runtime.h>
#include <math.h>

#define BB 128
#define HID 512
#define EMB 1024
#define N1 1536   // 3*HID
#define N2 256

// ---------------- ws layout ----------------
// inp   : [128][1536] f32  @ 0        (786432 B)
// part  : [2][128][256] f32 @ 786432  (262144 B)
// hbuf  : [128][256] f32   @ 1048576 (131072 B)
// scale : [256] f32        @ 1179648
// shift : [256] f32        @ 1180672
#define OFF_INP   0
#define OFF_PART  786432
#define OFF_HBUF  1048576
#define OFF_SCALE 1179648
#define OFF_SHIFT 1180672

__device__ __forceinline__ int lower_bound_i(const int* __restrict__ a, int n, int key) {
    int lo = 0, hi = n;
    while (lo < hi) {
        int mid = (lo + hi) >> 1;
        if (a[mid] < key) lo = mid + 1; else hi = mid;
    }
    return lo;
}

// K1: inp[b][s*512+h] = dot(emb[sample[b][s]], t_w[h]) + t_b[h] (+ p_feature[u/v][h])
// grid (3, 8, 8): s, 16-row tile, 64-h tile. block 256.
__global__ __launch_bounds__(256)
void k1_proj(const int* __restrict__ sample, const int* __restrict__ gb, int n_nodes,
             const float* __restrict__ p_feature,
             const float* __restrict__ tweet_emb, const float* __restrict__ desc_emb,
             const float* __restrict__ t_w, const float* __restrict__ t_b,
             float* __restrict__ inp)
{
    const int s  = blockIdx.x;
    const int bt = blockIdx.y;
    const int ht = blockIdx.z;
    const int t  = threadIdx.x;

    __shared__ float e_lds[16 * 132];   // +4 pad: 2-way bank alias only (free)
    __shared__ float w_lds[64 * 132];
    __shared__ int   idx_lds[16];
    __shared__ int   node_lds[16];

    if (t < 16) {
        const int b = bt * 16 + t;
        idx_lds[t] = sample[b * 3 + s];
        if (s != 1) {
            int u = lower_bound_i(gb, n_nodes, b);   // searchsorted left
            node_lds[t] = (s == 2) ? (u + 1) : u;
        }
    }
    __syncthreads();

    const float* __restrict__ emb = (s == 1) ? tweet_emb : desc_emb;

    const int er = t >> 4;            // 0..15 (row of e tile)
    const int ek = (t & 15) * 8;      // 0..120
    const float* erow = emb + (size_t)idx_lds[er] * EMB;

    const int wr = t >> 2;            // 0..63 (row of w tile)
    const int wk = (t & 3) * 32;      // 0,32,64,96
    const float* wrow = t_w + (size_t)(ht * 64 + wr) * EMB;

    const int r0 = (t & 7) * 2;       // 2-row register tile
    const int h0 = (t >> 3) * 2;      // 2-col register tile
    float acc[2][2] = {{0.f, 0.f}, {0.f, 0.f}};

    for (int kt = 0; kt < 8; ++kt) {
        const int kb = kt * 128;
        {
            const float* src = erow + kb + ek;
            float4 a0 = *(const float4*)(src);
            float4 a1 = *(const float4*)(src + 4);
            *(float4*)&e_lds[er * 132 + ek]     = a0;
            *(float4*)&e_lds[er * 132 + ek + 4] = a1;
        }
        {
            const float* src = wrow + kb + wk;
            float4* dst = (float4*)&w_lds[wr * 132 + wk];
            #pragma unroll
            for (int i = 0; i < 8; ++i) dst[i] = *(const float4*)(src + i * 4);
        }
        __syncthreads();
        #pragma unroll
        for (int kk = 0; kk < 128; kk += 4) {
            float4 ea = *(const float4*)&e_lds[r0 * 132 + kk];
            float4 eb = *(const float4*)&e_lds[(r0 + 1) * 132 + kk];
            float4 wa = *(const float4*)&w_lds[h0 * 132 + kk];
            float4 wb = *(const float4*)&w_lds[(h0 + 1) * 132 + kk];
            acc[0][0] += ea.x*wa.x + ea.y*wa.y + ea.z*wa.z + ea.w*wa.w;
            acc[0][1] += ea.x*wb.x + ea.y*wb.y + ea.z*wb.z + ea.w*wb.w;
            acc[1][0] += eb.x*wa.x + eb.y*wa.y + eb.z*wa.z + eb.w*wa.w;
            acc[1][1] += eb.x*wb.x + eb.y*wb.y + eb.z*wb.z + eb.w*wb.w;
        }
        __syncthreads();
    }

    #pragma unroll
    for (int rr = 0; rr < 2; ++rr) {
        const int r  = r0 + rr;
        const int b  = bt * 16 + r;
        const int gh = ht * 64 + h0;
        float v0 = acc[rr][0] + t_b[gh];
        float v1 = acc[rr][1] + t_b[gh + 1];
        if (s != 1) {
            const float* prow = p_feature + (size_t)node_lds[r] * HID;
            v0 += prow[gh];
            v1 += prow[gh + 1];
        }
        float* drow = inp + (size_t)b * N1 + s * HID + gh;
        drow[0] = v0;
        drow[1] = v1;
    }
}

// K2: part[ks][b][j] = sum_{k in ks-half} inp[b][k] * w1[j][k]
// grid (8, 8, 2): 16-row tile, 32-col tile, K split 2x768. block 256.
__global__ __launch_bounds__(256)
void k2_gemm(const float* __restrict__ inp, const float* __restrict__ w1,
             float* __restrict__ part)
{
    const int bt = blockIdx.x;
    const int jt = blockIdx.y;
    const int ks = blockIdx.z;
    const int t  = threadIdx.x;

    __shared__ float e_lds[16 * 132];
    __shared__ float w_lds[32 * 132];

    const int er = t >> 4;
    const int ek = (t & 15) * 8;
    const int wr = t >> 3;            // 0..31
    const int wk = (t & 7) * 16;      // 0..112

    const float* erow = inp + (size_t)(bt * 16 + er) * N1 + ks * 768;
    const float* wrow = w1  + (size_t)(jt * 32 + wr) * N1 + ks * 768;

    const int r  = t & 15;
    const int h0 = (t >> 4) * 2;
    float acc0 = 0.f, acc1 = 0.f;

    for (int kt = 0; kt < 6; ++kt) {
        const int kb = kt * 128;
        {
            const float* src = erow + kb + ek;
            *(float4*)&e_lds[er * 132 + ek]     = *(const float4*)(src);
            *(float4*)&e_lds[er * 132 + ek + 4] = *(const float4*)(src + 4);
        }
        {
            const float* src = wrow + kb + wk;
            float4* dst = (float4*)&w_lds[wr * 132 + wk];
            #pragma unroll
            for (int i = 0; i < 4; ++i) dst[i] = *(const float4*)(src + i * 4);
        }
        __syncthreads();
        #pragma unroll
        for (int kk = 0; kk < 128; kk += 4) {
            float4 ev = *(const float4*)&e_lds[r * 132 + kk];
            float4 wa = *(const float4*)&w_lds[h0 * 132 + kk];
            float4 wb = *(const float4*)&w_lds[(h0 + 1) * 132 + kk];
            acc0 += ev.x*wa.x + ev.y*wa.y + ev.z*wa.z + ev.w*wa.w;
            acc1 += ev.x*wb.x + ev.y*wb.y + ev.z*wb.z + ev.w*wb.w;
        }
        __syncthreads();
    }

    const int b = bt * 16 + r;
    const int j = jt * 32 + h0;
    float* dst = part + (size_t)ks * (BB * N2) + b * N2 + j;
    dst[0] = acc0;
    dst[1] = acc1;
}

// K3a: h = part0+part1+b1 -> hbuf; per-column mean/var -> scale/shift
// grid 8 blocks x 256 (each block: 32 columns)
__global__ __launch_bounds__(256)
void k3a_stats(const float* __restrict__ part, const float* __restrict__ b1,
               const float* __restrict__ gamma, const float* __restrict__ beta,
               float* __restrict__ hbuf, float* __restrict__ scale,
               float* __restrict__ shift)
{
    const int bl = blockIdx.x;
    const int t  = threadIdx.x;
    const int j  = bl * 32 + (t & 31);
    const int q  = t >> 5;            // 0..7 -> 16 rows each

    const float bias = b1[j];
    float sum = 0.f, sq = 0.f;
    #pragma unroll 4
    for (int i = 0; i < 16; ++i) {
        const int b = q * 16 + i;
        float v = part[b * N2 + j] + part[BB * N2 + b * N2 + j] + bias;
        hbuf[b * N2 + j] = v;
        sum += v;
        sq  += v * v;
    }

    __shared__ float s_sum[8][32];
    __shared__ float s_sq[8][32];
    s_sum[q][t & 31] = sum;
    s_sq[q][t & 31]  = sq;
    __syncthreads();

    if (t < 32) {
        float S = 0.f, Q = 0.f;
        #pragma unroll
        for (int q2 = 0; q2 < 8; ++q2) { S += s_sum[q2][t]; Q += s_sq[q2][t]; }
        const float mu  = S * (1.0f / 128.0f);
        const float var = Q * (1.0f / 128.0f) - mu * mu;   // biased batch var
        const float rs  = rsqrtf(var + 1e-5f);
        const int jj = bl * 32 + t;
        const float sc = gamma[jj] * rs;
        scale[jj] = sc;
        shift[jj] = beta[jj] - mu * sc;
    }
}

// K3b: out[b] = sigmoid( sum_j relu(h*scale+shift) * w2[j] + b2 )
// grid 16 blocks x 256 (4 waves, 2 rows per wave)
__global__ __launch_bounds__(256)
void k3b_out(const float* __restrict__ hbuf, const float* __restrict__ scale,
             const float* __restrict__ shift, const float* __restrict__ w2,
             const float* __restrict__ b2, float* __restrict__ out)
{
    const int t  = threadIdx.x;
    const int wv = t >> 6;
    const int l  = t & 63;
    const int b0 = blockIdx.x * 8 + wv * 2;

    #pragma unroll
    for (int rr = 0; rr < 2; ++rr) {
        const int b = b0 + rr;
        float acc = 0.f;
        #pragma unroll
        for (int i = 0; i < 4; ++i) {
            const int j = l + i * 64;
            float x = hbuf[b * N2 + j] * scale[j] + shift[j];
            x = fmaxf(x, 0.f);
            acc += x * w2[j];
        }
        #pragma unroll
        for (int off = 32; off; off >>= 1) acc += __shfl_xor(acc, off);
        if (l == 0) out[b] = 1.0f / (1.0f + expf(-(acc + b2[0])));
    }
}

extern "C" void kernel_launch(void* const* d_in, const int* in_sizes, int n_in,
                              void* d_out, int out_size, void* d_ws, size_t ws_size,
                              hipStream_t stream) {
    const int*   sample    = (const int*)  d_in[0];
    const int*   gb        = (const int*)  d_in[1];
    const float* p_feature = (const float*)d_in[2];
    const float* tweet_emb = (const float*)d_in[3];
    const float* desc_emb  = (const float*)d_in[4];
    const float* t_w       = (const float*)d_in[5];
    const float* t_b       = (const float*)d_in[6];
    const float* w1        = (const float*)d_in[7];
    const float* b1        = (const float*)d_in[8];
    const float* gamma     = (const float*)d_in[9];
    const float* beta      = (const float*)d_in[10];
    const float* w2        = (const float*)d_in[11];
    const float* b2        = (const float*)d_in[12];
    float* out = (float*)d_out;

    char* ws = (char*)d_ws;
    float* inp   = (float*)(ws + OFF_INP);
    float* part  = (float*)(ws + OFF_PART);
    float* hbuf  = (float*)(ws + OFF_HBUF);
    float* scale = (float*)(ws + OFF_SCALE);
    float* shift = (float*)(ws + OFF_SHIFT);
    const int n_nodes = in_sizes[1];

    k1_proj<<<dim3(3, 8, 8), 256, 0, stream>>>(sample, gb, n_nodes, p_feature,
                                               tweet_emb, desc_emb, t_w, t_b, inp);
    k2_gemm<<<dim3(8, 8, 2), 256, 0, stream>>>(inp, w1, part);
    k3a_stats<<<8, 256, 0, stream>>>(part, b1, gamma, beta, hbuf, scale, shift);
    k3b_out<<<16, 256, 0, stream>>>(hbuf, scale, shift, w2, b2, out);
}

// Round 2
// 27.773 us; speedup vs baseline: 2.2397x; 2.2397x over previous
//
#include <hip/hip_runtime.h>
#include <math.h>

#define BB 128
#define HID 512
#define EMB 1024
#define N1 1536
#define N2 256

typedef __attribute__((ext_vector_type(8))) __bf16 bf16x8;
typedef __attribute__((ext_vector_type(4))) __bf16 bf16x4;
typedef __attribute__((ext_vector_type(4))) float fx4;

// ---------------- ws layout (bytes) ----------------
#define OFF_ABUF 0            // [384][1024] bf16   = 786432
#define OFF_TWB  786432       // [512][1024] bf16   = 1048576
#define OFF_W1B  1835008      // [256][1536] bf16   = 786432
#define OFF_INPB 2621440      // [384][512]  bf16   = 393216
#define OFF_P1   3014656      // [4][384][512] f32  = 3145728
#define OFF_P2   6160384      // [4][128][256] f32  = 524288
#define OFF_H    6684672      // [128][256] f32     = 131072
#define OFF_SC   6815744      // [256] f32
#define OFF_SH   6816768      // [256] f32
#define OFF_UIDX 6817792      // [128] i32

__device__ __forceinline__ fx4 mfma16(bf16x8 a, bf16x8 b, fx4 c) {
    return __builtin_amdgcn_mfma_f32_16x16x32_bf16(a, b, c, 0, 0, 0);
}

// LDS tile: [64 rows][64 k] bf16, 16B-granule XOR swizzle: granule g of row r
// lives at physical granule g ^ (r&7).  (T2; read side applies same XOR.)
__device__ __forceinline__ int lds_idx(int row, int g) {
    return row * 64 + ((g ^ (row & 7)) * 8);
}

// ---------------- A: gather + f32->bf16 convert + u_idx scatter ----------------
// blocks 0..383: Abuf row (s*128+b); 384..895: t_w row; 896..1151: w1 row;
// 1152..: u_idx scatter over nodes.
__global__ __launch_bounds__(256)
void kA_prep(const int* __restrict__ sample, const int* __restrict__ gb, int n_nodes,
             const float* __restrict__ tweet_emb, const float* __restrict__ desc_emb,
             const float* __restrict__ t_w, const float* __restrict__ w1,
             __bf16* __restrict__ Abuf, __bf16* __restrict__ twb,
             __bf16* __restrict__ w1b, int* __restrict__ uidx)
{
    const int blk = blockIdx.x;
    const int t   = threadIdx.x;

    if (blk < 384) {
        const int s = blk >> 7, b = blk & 127;
        const int id = sample[b * 3 + s];
        const float* src = (s == 1) ? (tweet_emb + (size_t)id * EMB)
                                    : (desc_emb + (size_t)id * EMB);
        float4 v = *(const float4*)(src + t * 4);
        bf16x4 o = {(__bf16)v.x, (__bf16)v.y, (__bf16)v.z, (__bf16)v.w};
        *(bf16x4*)(Abuf + (size_t)blk * EMB + t * 4) = o;
    } else if (blk < 896) {
        const int r = blk - 384;
        float4 v = *(const float4*)(t_w + (size_t)r * EMB + t * 4);
        bf16x4 o = {(__bf16)v.x, (__bf16)v.y, (__bf16)v.z, (__bf16)v.w};
        *(bf16x4*)(twb + (size_t)r * EMB + t * 4) = o;
    } else if (blk < 1152) {
        const int r = blk - 896;
        for (int i = t; i < 384; i += 256) {
            float4 v = *(const float4*)(w1 + (size_t)r * N1 + i * 4);
            bf16x4 o = {(__bf16)v.x, (__bf16)v.y, (__bf16)v.z, (__bf16)v.w};
            *(bf16x4*)(w1b + (size_t)r * N1 + i * 4) = o;
        }
    } else {
        const int n = (blk - 1152) * 256 + t;
        if (n < n_nodes) {
            const int g = gb[n];
            if (n == 0 || gb[n - 1] != g) uidx[g] = n;
        }
    }
}

// ---------------- B: K1 GEMM  part1[ks][m][n] = Abuf[m][kslice] . twb[n][kslice]
// grid (8 n-tiles, 6 m-tiles, 4 k-splits), 256 threads (4 waves, 32x32 each).
__global__ __launch_bounds__(256)
void kB_gemm1(const __bf16* __restrict__ Abuf, const __bf16* __restrict__ twb,
              float* __restrict__ part1)
{
    const int n0 = blockIdx.x * 64;
    const int m0 = blockIdx.y * 64;
    const int ks = blockIdx.z;
    const int t  = threadIdx.x;
    const int wid = t >> 6, l = t & 63;
    const int mbase = (wid >> 1) * 32, nbase = (wid & 1) * 32;

    __shared__ __bf16 Alds[64 * 64];
    __shared__ __bf16 Blds[64 * 64];

    const int srow = t >> 2;          // staging row 0..63
    const int g0   = (t & 3) * 2;     // granule pair

    fx4 acc[2][2] = {};

    bf16x8 av0, av1, bv0, bv1;
    {
        const int k0 = ks * 256;
        const __bf16* ap = Abuf + (size_t)(m0 + srow) * EMB + k0 + g0 * 8;
        const __bf16* bp = twb  + (size_t)(n0 + srow) * EMB + k0 + g0 * 8;
        av0 = *(const bf16x8*)ap; av1 = *(const bf16x8*)(ap + 8);
        bv0 = *(const bf16x8*)bp; bv1 = *(const bf16x8*)(bp + 8);
    }

    for (int kt = 0; kt < 4; ++kt) {
        __syncthreads();
        *(bf16x8*)&Alds[lds_idx(srow, g0)]     = av0;
        *(bf16x8*)&Alds[lds_idx(srow, g0 + 1)] = av1;
        *(bf16x8*)&Blds[lds_idx(srow, g0)]     = bv0;
        *(bf16x8*)&Blds[lds_idx(srow, g0 + 1)] = bv1;
        __syncthreads();

        if (kt < 3) {
            const int k0 = ks * 256 + (kt + 1) * 64;
            const __bf16* ap = Abuf + (size_t)(m0 + srow) * EMB + k0 + g0 * 8;
            const __bf16* bp = twb  + (size_t)(n0 + srow) * EMB + k0 + g0 * 8;
            av0 = *(const bf16x8*)ap; av1 = *(const bf16x8*)(ap + 8);
            bv0 = *(const bf16x8*)bp; bv1 = *(const bf16x8*)(bp + 8);
        }

        #pragma unroll
        for (int kq = 0; kq < 2; ++kq) {
            const int g = kq * 4 + (l >> 4);
            bf16x8 a0 = *(const bf16x8*)&Alds[lds_idx(mbase +      (l & 15), g)];
            bf16x8 a1 = *(const bf16x8*)&Alds[lds_idx(mbase + 16 + (l & 15), g)];
            bf16x8 b0 = *(const bf16x8*)&Blds[lds_idx(nbase +      (l & 15), g)];
            bf16x8 b1 = *(const bf16x8*)&Blds[lds_idx(nbase + 16 + (l & 15), g)];
            acc[0][0] = mfma16(a0, b0, acc[0][0]);
            acc[0][1] = mfma16(a0, b1, acc[0][1]);
            acc[1][0] = mfma16(a1, b0, acc[1][0]);
            acc[1][1] = mfma16(a1, b1, acc[1][1]);
        }
    }

    float* dst = part1 + (size_t)ks * (384 * 512);
    #pragma unroll
    for (int mi = 0; mi < 2; ++mi)
        #pragma unroll
        for (int ni = 0; ni < 2; ++ni) {
            const int row = m0 + mbase + mi * 16 + (l >> 4) * 4;
            const int col = n0 + nbase + ni * 16 + (l & 15);
            #pragma unroll
            for (int j = 0; j < 4; ++j)
                dst[(size_t)(row + j) * 512 + col] = acc[mi][ni][j];
        }
}

// ---------------- C: combine K1 partials + t_b + p_feature gather -> inp_bf (bf16)
// grid 192 x 256: block = 2 rows of [384][512].
__global__ __launch_bounds__(256)
void kC_comb1(const float* __restrict__ part1, const float* __restrict__ t_b,
              const float* __restrict__ p_feature, const int* __restrict__ uidx,
              __bf16* __restrict__ inp_bf)
{
    const int t = threadIdx.x;
    const int m = blockIdx.x * 2 + (t >> 7);
    const int j0 = (t & 127) * 4;
    const int s = m >> 7, b = m & 127;

    float4 v = *(const float4*)(part1 + (size_t)m * 512 + j0);
    #pragma unroll
    for (int p = 1; p < 4; ++p) {
        float4 q = *(const float4*)(part1 + (size_t)p * (384 * 512) + (size_t)m * 512 + j0);
        v.x += q.x; v.y += q.y; v.z += q.z; v.w += q.w;
    }
    float4 tb = *(const float4*)(t_b + j0);
    v.x += tb.x; v.y += tb.y; v.z += tb.z; v.w += tb.w;
    if (s != 1) {
        const int node = (s == 0) ? uidx[b] : (uidx[b] + 1);
        float4 pf = *(const float4*)(p_feature + (size_t)node * HID + j0);
        v.x += pf.x; v.y += pf.y; v.z += pf.z; v.w += pf.w;
    }
    bf16x4 o = {(__bf16)v.x, (__bf16)v.y, (__bf16)v.z, (__bf16)v.w};
    *(bf16x4*)(inp_bf + (size_t)m * 512 + j0) = o;
}

// ---------------- D: K2 GEMM  part2[ks][b][n] = inp[b][kslice] . w1[n][kslice]
// inp logical [128][1536], physical inp_bf[(k>>9)*128 + b][k&511].
// grid (4 n-tiles, 2 m-tiles, 4 k-splits of 384), 256 threads.
__global__ __launch_bounds__(256)
void kD_gemm2(const __bf16* __restrict__ inp_bf, const __bf16* __restrict__ w1b,
              float* __restrict__ part2)
{
    const int n0 = blockIdx.x * 64;
    const int m0 = blockIdx.y * 64;
    const int ks = blockIdx.z;
    const int t  = threadIdx.x;
    const int wid = t >> 6, l = t & 63;
    const int mbase = (wid >> 1) * 32, nbase = (wid & 1) * 32;

    __shared__ __bf16 Alds[64 * 64];
    __shared__ __bf16 Blds[64 * 64];

    const int srow = t >> 2;
    const int g0   = (t & 3) * 2;

    fx4 acc[2][2] = {};

    bf16x8 av0, av1, bv0, bv1;
    {
        const int k0 = ks * 384;
        const __bf16* ap = inp_bf + (size_t)((k0 >> 9) * 128 + m0 + srow) * HID + (k0 & 511) + g0 * 8;
        const __bf16* bp = w1b + (size_t)(n0 + srow) * N1 + k0 + g0 * 8;
        av0 = *(const bf16x8*)ap; av1 = *(const bf16x8*)(ap + 8);
        bv0 = *(const bf16x8*)bp; bv1 = *(const bf16x8*)(bp + 8);
    }

    for (int kt = 0; kt < 6; ++kt) {
        __syncthreads();
        *(bf16x8*)&Alds[lds_idx(srow, g0)]     = av0;
        *(bf16x8*)&Alds[lds_idx(srow, g0 + 1)] = av1;
        *(bf16x8*)&Blds[lds_idx(srow, g0)]     = bv0;
        *(bf16x8*)&Blds[lds_idx(srow, g0 + 1)] = bv1;
        __syncthreads();

        if (kt < 5) {
            const int k0 = ks * 384 + (kt + 1) * 64;
            const __bf16* ap = inp_bf + (size_t)((k0 >> 9) * 128 + m0 + srow) * HID + (k0 & 511) + g0 * 8;
            const __bf16* bp = w1b + (size_t)(n0 + srow) * N1 + k0 + g0 * 8;
            av0 = *(const bf16x8*)ap; av1 = *(const bf16x8*)(ap + 8);
            bv0 = *(const bf16x8*)bp; bv1 = *(const bf16x8*)(bp + 8);
        }

        #pragma unroll
        for (int kq = 0; kq < 2; ++kq) {
            const int g = kq * 4 + (l >> 4);
            bf16x8 a0 = *(const bf16x8*)&Alds[lds_idx(mbase +      (l & 15), g)];
            bf16x8 a1 = *(const bf16x8*)&Alds[lds_idx(mbase + 16 + (l & 15), g)];
            bf16x8 b0 = *(const bf16x8*)&Blds[lds_idx(nbase +      (l & 15), g)];
            bf16x8 b1 = *(const bf16x8*)&Blds[lds_idx(nbase + 16 + (l & 15), g)];
            acc[0][0] = mfma16(a0, b0, acc[0][0]);
            acc[0][1] = mfma16(a0, b1, acc[0][1]);
            acc[1][0] = mfma16(a1, b0, acc[1][0]);
            acc[1][1] = mfma16(a1, b1, acc[1][1]);
        }
    }

    float* dst = part2 + (size_t)ks * (128 * 256);
    #pragma unroll
    for (int mi = 0; mi < 2; ++mi)
        #pragma unroll
        for (int ni = 0; ni < 2; ++ni) {
            const int row = m0 + mbase + mi * 16 + (l >> 4) * 4;
            const int col = n0 + nbase + ni * 16 + (l & 15);
            #pragma unroll
            for (int j = 0; j < 4; ++j)
                dst[(size_t)(row + j) * 256 + col] = acc[mi][ni][j];
        }
}

// ---------------- E: combine K2 partials + b1 -> h; BN batch stats -> scale/shift
__global__ __launch_bounds__(256)
void kE_stats(const float* __restrict__ part2, const float* __restrict__ b1,
              const float* __restrict__ gamma, const float* __restrict__ beta,
              float* __restrict__ hbuf, float* __restrict__ scale,
              float* __restrict__ shift)
{
    const int bl = blockIdx.x;
    const int t  = threadIdx.x;
    const int j  = bl * 32 + (t & 31);
    const int q  = t >> 5;

    const float bias = b1[j];
    float sum = 0.f, sq = 0.f;
    for (int i = 0; i < 16; ++i) {
        const int b = q * 16 + i;
        float v = bias;
        #pragma unroll
        for (int p = 0; p < 4; ++p)
            v += part2[(size_t)p * (128 * 256) + b * N2 + j];
        hbuf[b * N2 + j] = v;
        sum += v;
        sq  += v * v;
    }

    __shared__ float s_sum[8][32];
    __shared__ float s_sq[8][32];
    s_sum[q][t & 31] = sum;
    s_sq[q][t & 31]  = sq;
    __syncthreads();

    if (t < 32) {
        float S = 0.f, Q = 0.f;
        #pragma unroll
        for (int q2 = 0; q2 < 8; ++q2) { S += s_sum[q2][t]; Q += s_sq[q2][t]; }
        const float mu  = S * (1.0f / 128.0f);
        const float var = Q * (1.0f / 128.0f) - mu * mu;
        const float rs  = rsqrtf(var + 1e-5f);
        const int jj = bl * 32 + t;
        const float sc = gamma[jj] * rs;
        scale[jj] = sc;
        shift[jj] = beta[jj] - mu * sc;
    }
}

// ---------------- F: normalize+ReLU+dot(w2)+sigmoid ----------------
__global__ __launch_bounds__(256)
void kF_out(const float* __restrict__ hbuf, const float* __restrict__ scale,
            const float* __restrict__ shift, const float* __restrict__ w2,
            const float* __restrict__ b2, float* __restrict__ out)
{
    const int t  = threadIdx.x;
    const int wv = t >> 6;
    const int l  = t & 63;
    const int b0 = blockIdx.x * 8 + wv * 2;

    #pragma unroll
    for (int rr = 0; rr < 2; ++rr) {
        const int b = b0 + rr;
        float acc = 0.f;
        #pragma unroll
        for (int i = 0; i < 4; ++i) {
            const int j = l + i * 64;
            float x = hbuf[b * N2 + j] * scale[j] + shift[j];
            x = fmaxf(x, 0.f);
            acc += x * w2[j];
        }
        #pragma unroll
        for (int off = 32; off; off >>= 1) acc += __shfl_xor(acc, off);
        if (l == 0) out[b] = 1.0f / (1.0f + expf(-(acc + b2[0])));
    }
}

extern "C" void kernel_launch(void* const* d_in, const int* in_sizes, int n_in,
                              void* d_out, int out_size, void* d_ws, size_t ws_size,
                              hipStream_t stream) {
    const int*   sample    = (const int*)  d_in[0];
    const int*   gb        = (const int*)  d_in[1];
    const float* p_feature = (const float*)d_in[2];
    const float* tweet_emb = (const float*)d_in[3];
    const float* desc_emb  = (const float*)d_in[4];
    const float* t_w       = (const float*)d_in[5];
    const float* t_b       = (const float*)d_in[6];
    const float* w1        = (const float*)d_in[7];
    const float* b1        = (const float*)d_in[8];
    const float* gamma     = (const float*)d_in[9];
    const float* beta      = (const float*)d_in[10];
    const float* w2        = (const float*)d_in[11];
    const float* b2        = (const float*)d_in[12];
    float* out = (float*)d_out;

    char* ws = (char*)d_ws;
    __bf16* Abuf   = (__bf16*)(ws + OFF_ABUF);
    __bf16* twb    = (__bf16*)(ws + OFF_TWB);
    __bf16* w1b    = (__bf16*)(ws + OFF_W1B);
    __bf16* inp_bf = (__bf16*)(ws + OFF_INPB);
    float*  part1  = (float*)(ws + OFF_P1);
    float*  part2  = (float*)(ws + OFF_P2);
    float*  hbuf   = (float*)(ws + OFF_H);
    float*  scale  = (float*)(ws + OFF_SC);
    float*  shift  = (float*)(ws + OFF_SH);
    int*    uidx   = (int*)  (ws + OFF_UIDX);

    const int n_nodes = in_sizes[1];
    const int scatter_blocks = (n_nodes + 255) / 256;

    kA_prep<<<1152 + scatter_blocks, 256, 0, stream>>>(sample, gb, n_nodes,
        tweet_emb, desc_emb, t_w, w1, Abuf, twb, w1b, uidx);
    kB_gemm1<<<dim3(8, 6, 4), 256, 0, stream>>>(Abuf, twb, part1);
    kC_comb1<<<192, 256, 0, stream>>>(part1, t_b, p_feature, uidx, inp_bf);
    kD_gemm2<<<dim3(4, 2, 4), 256, 0, stream>>>(inp_bf, w1b, part2);
    kE_stats<<<8, 256, 0, stream>>>(part2, b1, gamma, beta, hbuf, scale, shift);
    kF_out<<<16, 256, 0, stream>>>(hbuf, scale, shift, w2, b2, out);
}